// Round 9
// baseline (211.635 us; speedup 1.0000x reference)
//
#include <hip/hip_runtime.h>
#include <hip/hip_bf16.h>

typedef __bf16 bf16_t;
typedef bf16_t bf16x8 __attribute__((ext_vector_type(8)));
typedef float  f32x4  __attribute__((ext_vector_type(4)));

constexpr int S = 2048, D = 256;

// ---------------- ws layout (bytes) ----------------
// wtf   : [2][16 nt][8 ks][64 lane][8] bf16 (frag W^T q,k)  @ 0        (262144)
// q     : frag layout [B][128 qb][8 ks][64 lane][8] bf16    @ 262144   (16777216)
// k     : frag layout [B][128 kb][8 ks][64 lane][8] bf16    @ 17039360 (16777216)
// lpart : [4 kh][16 b][2048] f32                            @ 33816576 (524288)
// wpart : [4 qt][16 b][2048] f32                            @ 34340864 (524288)
// gpart : [16 kseg][16 b][256] f32                          @ 34865152 (262144)
// total : 35127296 (~35.1 MB).  V is NEVER materialized:
//   out = (sum_k w_k x_k) @ Wv + 2048*bv   (sum_k w_k == #queries exactly)

__device__ __forceinline__ float fast_exp2(float x) {
    return __builtin_amdgcn_exp2f(x);
}

// Kernel 1: Wq/Wk -> bf16 fragment-major.
__global__ void wt_kernel(const float* __restrict__ Wq, const float* __restrict__ Wk,
                          bf16_t* __restrict__ wtf) {
    int idx = blockIdx.x * 256 + threadIdx.x;   // [0, 16384)
    int w    = idx >> 13;
    int rem  = idx & 8191;
    int nt   = rem >> 9;
    int rem2 = rem & 511;
    int ks   = rem2 >> 6;
    int lane = rem2 & 63;
    int lm = lane & 15, lg = lane >> 4;
    const float* Wsrc = (w == 0) ? Wq : Wk;
    int col = nt * 16 + lm, krow = ks * 32 + lg * 8;
    bf16x8 o;
#pragma unroll
    for (int j = 0; j < 8; j++) o[j] = (bf16_t)Wsrc[(krow + j) * 256 + col];
    *(bf16x8*)(wtf + (size_t)idx * 8) = o;
}

// Kernel 2: Q/K projection, GEMM-tiled. grid (512 = 256 rowb x 2 colh, 2 w),
// 256 thr (4 waves as 2 rowg x 2 colg). Block tile 128 rows x 128 cols.
// The block's 64 KB of B-frags staged to LDS ONCE (one barrier total);
// each wave holds 4 A-sets (64 rows) in regs -> B-frag reuse 4.
// Per CU (2 blocks): MFMA ~4966 cyc vs LDS ~3072 cyc -> MFMA-bound.
__global__ __launch_bounds__(256, 2) void proj_kernel(
    const float* __restrict__ x, const bf16_t* __restrict__ wtf,
    const float* __restrict__ bq, const float* __restrict__ bk,
    bf16_t* __restrict__ qo, bf16_t* __restrict__ ko) {
    __shared__ bf16_t bst[32768];          // 8 nt x 8 ks x 512  (64 KB)
    __shared__ bf16_t sb_all[4][1152];     // epilogue transpose: 16 x 72 per wave
    int w    = blockIdx.y;
    int tid  = threadIdx.x;
    int wave = tid >> 6, lane = tid & 63, lm = lane & 15, lg = lane >> 4;
    int rowb = blockIdx.x >> 1;
    int colh = blockIdx.x & 1;
    int rowg = wave >> 1, colg = wave & 1;
    const bf16_t* wb   = wtf + w * 65536;
    const float*  bias = (w == 0) ? bq : bk;

    // ---- stage this col-half's B-frags (64 KB) ----
    {
        const bf16_t* src = wb + (size_t)colh * 32768;
#pragma unroll
        for (int u = 0; u < 16; u++) {
            int c = u * 256 + tid;
            *(bf16x8*)&bst[(size_t)c * 8] = *(const bf16x8*)(src + (size_t)c * 8);
        }
    }

    // ---- A-frags: 4 sets x 16 rows, direct from fp32 x (contig 32B/lane) ----
    int m0 = rowb * 128 + rowg * 64;
    bf16x8 af[4][8];
#pragma unroll
    for (int s = 0; s < 4; s++) {
        const float* xr = x + (size_t)(m0 + s * 16 + lm) * 256 + lg * 8;
#pragma unroll
        for (int ks = 0; ks < 8; ks++) {
            float4 a0 = *(const float4*)(xr + ks * 32);
            float4 a1 = *(const float4*)(xr + ks * 32 + 4);
            af[s][ks][0] = (bf16_t)a0.x; af[s][ks][1] = (bf16_t)a0.y;
            af[s][ks][2] = (bf16_t)a0.z; af[s][ks][3] = (bf16_t)a0.w;
            af[s][ks][4] = (bf16_t)a1.x; af[s][ks][5] = (bf16_t)a1.y;
            af[s][ks][6] = (bf16_t)a1.z; af[s][ks][7] = (bf16_t)a1.w;
        }
    }
    __syncthreads();

    // ---- MFMA: 4 sets x 4 nt x 8 ks = 128 MFMAs, B from LDS (reuse 4) ----
    f32x4 acc[4][4];
#pragma unroll
    for (int s = 0; s < 4; s++)
#pragma unroll
        for (int nt = 0; nt < 4; nt++) acc[s][nt] = f32x4{0.f, 0.f, 0.f, 0.f};
#pragma unroll
    for (int ks = 0; ks < 8; ks++) {
#pragma unroll
        for (int nt = 0; nt < 4; nt++) {
            bf16x8 bfr = *(const bf16x8*)&bst[(size_t)(((colg * 4 + nt) * 8 + ks) * 512) + lane * 8];
#pragma unroll
            for (int s = 0; s < 4; s++)
                acc[s][nt] = __builtin_amdgcn_mfma_f32_16x16x32_bf16(af[s][ks], bfr, acc[s][nt], 0, 0, 0);
        }
    }

    // ---- epilogue: wave-private LDS transpose -> frag-major 16B stores ----
    bf16_t* sb = sb_all[wave];
    int bglob = m0 >> 11;
    bf16_t* dst = (w == 0) ? qo : ko;
    int c0 = colh * 128 + colg * 64;
#pragma unroll
    for (int s = 0; s < 4; s++) {
#pragma unroll
        for (int nt = 0; nt < 4; nt++) {
            int colloc = nt * 16 + lm;
            float bval = bias[c0 + colloc];
#pragma unroll
            for (int r = 0; r < 4; r++)
                sb[(lg * 4 + r) * 72 + colloc] = (bf16_t)(acc[s][nt][r] + bval);
        }
        int qb = ((m0 & 2047) >> 4) + s;
#pragma unroll
        for (int kk = 0; kk < 2; kk++) {
            bf16x8 v8 = *(const bf16x8*)&sb[lm * 72 + kk * 32 + lg * 8];
            *(bf16x8*)(dst + ((size_t)((bglob * 128 + qb) * 8 + (c0 >> 5) + kk)) * 512 + lane * 8) = v8;
        }
    }
}

// Kernels 3/4: QK^T passes. grid 256 = (16 b x 4 qt(512 rows) x 4 kh(512 keys)),
// 512 thr (8 waves). Wave owns 64 q-rows (4 A-sets in regs -> B-frag reuse 4);
// 64-key K tiles staged to LDS (2x32KB dbuf), shared by 8 waves.
// PASS=1: row-sums l -> lpart.  PASS=2: w_k = sum_q p/l -> wpart.
template <int PASS>
__global__ __launch_bounds__(512, 2) void attn_pass(
    const bf16_t* __restrict__ q, const bf16_t* __restrict__ kmat,
    float* __restrict__ lpart, float* __restrict__ wpart) {
    __shared__ bf16_t kst[2][16384];          // 2 x 32 KB
    __shared__ bf16_t wacc[8][512];           // PASS 2 only

    int tid  = threadIdx.x;
    int wave = tid >> 6, lane = tid & 63, lm = lane & 15, lg = lane >> 4;
    int i    = blockIdx.x;                    // 256 blocks
    int idx2 = i >> 3;                        // 0..31
    int qt   = idx2 & 3;
    int kh   = (idx2 >> 2) & 3;
    int b    = (i & 7) * 2 + (idx2 >> 4);     // XCD-aware: 2 batches per XCD

    // A-frags: 4 sets x 16 q-rows = 64 q-rows per wave (128 VGPRs).
    bf16x8 af[4][8];
#pragma unroll
    for (int s = 0; s < 4; s++) {
        const bf16_t* qb = q + ((size_t)((b * 128 + qt * 32 + wave * 4 + s) * 8)) * 512;
#pragma unroll
        for (int ks = 0; ks < 8; ks++)
            af[s][ks] = *(const bf16x8*)(qb + ks * 512 + lane * 8);
    }

    float rinv[4][4];
    if (PASS == 2) {
#pragma unroll
        for (int s = 0; s < 4; s++)
#pragma unroll
            for (int r = 0; r < 4; r++) {
                int row = qt * 512 + wave * 64 + s * 16 + lg * 4 + r;
                float l = 0.f;
#pragma unroll
                for (int k2 = 0; k2 < 4; k2++)
                    l += lpart[(size_t)(k2 * 16 + b) * 2048 + row];
                rinv[s][r] = 1.0f / l;
            }
    }

    float lsum[4][4];
#pragma unroll
    for (int s = 0; s < 4; s++)
#pragma unroll
        for (int r = 0; r < 4; r++) lsum[s][r] = 0.f;

    constexpr float SCL = 0.0625f * 1.44269504f;
    const bf16_t* kb_base = kmat + (size_t)(b * 128 + kh * 32) * 4096;

    bf16x8 stg[4];
#pragma unroll
    for (int u = 0; u < 4; u++)
        stg[u] = *(const bf16x8*)(kb_base + (size_t)(u * 512 + tid) * 8);

    for (int t = 0; t < 8; t++) {
        int p = t & 1;
#pragma unroll
        for (int u = 0; u < 4; u++)
            *(bf16x8*)&kst[p][(u * 512 + tid) * 8] = stg[u];
        if (t < 7) {
#pragma unroll
            for (int u = 0; u < 4; u++)
                stg[u] = *(const bf16x8*)(kb_base + (size_t)(t + 1) * 16384 + (u * 512 + tid) * 8);
        }
        __syncthreads();

#pragma unroll
        for (int h = 0; h < 2; h++) {
            f32x4 sacc[4][2];
#pragma unroll
            for (int s = 0; s < 4; s++) {
                sacc[s][0] = f32x4{0.f, 0.f, 0.f, 0.f};
                sacc[s][1] = f32x4{0.f, 0.f, 0.f, 0.f};
            }
#pragma unroll
            for (int ks = 0; ks < 8; ks++) {
                bf16x8 b0 = *(const bf16x8*)&kst[p][((h * 2 + 0) * 8 + ks) * 512 + lane * 8];
                bf16x8 b1 = *(const bf16x8*)&kst[p][((h * 2 + 1) * 8 + ks) * 512 + lane * 8];
#pragma unroll
                for (int s = 0; s < 4; s++) {
                    sacc[s][0] = __builtin_amdgcn_mfma_f32_16x16x32_bf16(af[s][ks], b0, sacc[s][0], 0, 0, 0);
                    sacc[s][1] = __builtin_amdgcn_mfma_f32_16x16x32_bf16(af[s][ks], b1, sacc[s][1], 0, 0, 0);
                }
            }
            if (PASS == 1) {
#pragma unroll
                for (int s = 0; s < 4; s++)
#pragma unroll
                    for (int j = 0; j < 2; j++)
#pragma unroll
                        for (int r = 0; r < 4; r++)
                            lsum[s][r] += fast_exp2(sacc[s][j][r] * SCL);
            } else {
#pragma unroll
                for (int j = 0; j < 2; j++) {
                    float wv = 0.f;
#pragma unroll
                    for (int s = 0; s < 4; s++)
#pragma unroll
                        for (int r = 0; r < 4; r++)
                            wv += fast_exp2(sacc[s][j][r] * SCL) * rinv[s][r];
                    wv += __shfl_xor(wv, 16);
                    wv += __shfl_xor(wv, 32);
                    if (lg == 0) wacc[wave][t * 64 + (h * 2 + j) * 16 + lm] = (bf16_t)wv;
                }
            }
        }
    }

    if (PASS == 1) {
#pragma unroll
        for (int s = 0; s < 4; s++)
#pragma unroll
            for (int r = 0; r < 4; r++) {
                float v2 = lsum[s][r];
                v2 += __shfl_xor(v2, 1);
                v2 += __shfl_xor(v2, 2);
                v2 += __shfl_xor(v2, 4);
                v2 += __shfl_xor(v2, 8);
                if (lm == 0) {
                    int row = qt * 512 + wave * 64 + s * 16 + lg * 4 + r;
                    lpart[(size_t)(kh * 16 + b) * 2048 + row] = v2;
                }
            }
    } else {
        __syncthreads();
        float sum = 0.f;
#pragma unroll
        for (int w2 = 0; w2 < 8; w2++) sum += (float)wacc[w2][tid];
        wpart[(size_t)(qt * 16 + b) * 2048 + kh * 512 + tid] = sum;
    }
}

// Kernel 5: gpart[kseg,b,d] = sum over 128 keys of w_k x[b,k,d] (fp32 x).
__global__ __launch_bounds__(256) void xsum_kernel(
    const float* __restrict__ wpart, const float* __restrict__ x,
    float* __restrict__ gpart) {
    __shared__ float ldsw[128];
    int b = blockIdx.x >> 4, kseg = blockIdx.x & 15, tid = threadIdx.x;
    if (tid < 128) {
        int key = kseg * 128 + tid;
        float s = 0.f;
#pragma unroll
        for (int qt = 0; qt < 4; qt++) s += wpart[(size_t)(qt * 16 + b) * 2048 + key];
        ldsw[tid] = s;
    }
    __syncthreads();
    const float* xb = x + ((size_t)b * 2048 + kseg * 128) * 256;
    float acc = 0.f;
#pragma unroll 8
    for (int t = 0; t < 128; t++) acc += ldsw[t] * xb[(size_t)t * 256 + tid];
    gpart[(size_t)(kseg * 16 + b) * 256 + tid] = acc;
}

// Kernel 6: out[b,d] = (sum_kseg gpart)[b,:] @ Wv[:,d] + 2048*bv[d].
__global__ __launch_bounds__(256) void final_kernel(
    const float* __restrict__ gpart, const float* __restrict__ Wv,
    const float* __restrict__ bv, float* __restrict__ out) {
    __shared__ float yl[256];
    int b = blockIdx.x, tid = threadIdx.x;
    float s = 0.f;
#pragma unroll
    for (int ks = 0; ks < 16; ks++) s += gpart[(size_t)(ks * 16 + b) * 256 + tid];
    yl[tid] = s;
    __syncthreads();
    float acc = 0.f;
#pragma unroll 4
    for (int c = 0; c < 256; c++) acc += yl[c] * Wv[c * 256 + tid];
    out[b * 256 + tid] = acc + 2048.0f * bv[tid];
}

extern "C" void kernel_launch(void* const* d_in, const int* in_sizes, int n_in,
                              void* d_out, int out_size, void* d_ws, size_t ws_size,
                              hipStream_t stream) {
    const float* x  = (const float*)d_in[0];
    const float* Wq = (const float*)d_in[1];
    const float* bq = (const float*)d_in[2];
    const float* Wk = (const float*)d_in[3];
    const float* bk = (const float*)d_in[4];
    const float* Wv = (const float*)d_in[5];
    const float* bv = (const float*)d_in[6];
    float* out = (float*)d_out;

    char* ws = (char*)d_ws;
    bf16_t* wtf   = (bf16_t*)(ws);
    bf16_t* q     = (bf16_t*)(ws + 262144);
    bf16_t* kmat  = (bf16_t*)(ws + 17039360);
    float*  lpart = (float*) (ws + 33816576);
    float*  wpart = (float*) (ws + 34340864);
    float*  gpart = (float*) (ws + 34865152);

    wt_kernel<<<dim3(64), dim3(256), 0, stream>>>(Wq, Wk, wtf);
    proj_kernel<<<dim3(512, 2), dim3(256), 0, stream>>>(x, wtf, bq, bk, q, kmat);
    attn_pass<1><<<dim3(256), dim3(512), 0, stream>>>(q, kmat, lpart, wpart);
    attn_pass<2><<<dim3(256), dim3(512), 0, stream>>>(q, kmat, lpart, wpart);
    xsum_kernel<<<dim3(256), dim3(256), 0, stream>>>(wpart, x, gpart);
    final_kernel<<<dim3(16), dim3(256), 0, stream>>>(gpart, Wv, bv, out);
}

// Round 10
// 188.962 us; speedup vs baseline: 1.1200x; 1.1200x over previous
//
#include <hip/hip_runtime.h>
#include <hip/hip_bf16.h>

typedef __bf16 bf16_t;
typedef bf16_t bf16x8 __attribute__((ext_vector_type(8)));
typedef bf16_t bf16x4 __attribute__((ext_vector_type(4)));
typedef float  f32x4  __attribute__((ext_vector_type(4)));

constexpr int S = 2048, D = 256;

// ---------------- ws layout (bytes) ----------------
// wtf   : [2][16 nt][8 ks][64 lane][8] bf16 (frag W^T q,k)  @ 0        (262144)
// xf    : frag layout [2048 qb][8 ks][64 lane][8] bf16      @ 262144   (16777216)
// q     : frag layout [B][128 qb][8 ks][64 lane][8] bf16    @ 17039360 (16777216)
// k     : frag layout [B][128 kb][8 ks][64 lane][8] bf16    @ 33816576 (16777216)
// lpart : [4 kh][16 b][2048] f32                            @ 50593792 (524288)
// wpart : [4 qt][16 b][2048] f32                            @ 51118080 (524288)
// gpart : [16 kseg][16 b][256] f32                          @ 51642368 (262144)
// total : 51904512 (~51.9 MB).  V is NEVER materialized:
//   out = (sum_k w_k x_k) @ Wv + 2048*bv   (sum_k w_k == #queries exactly)

__device__ __forceinline__ float fast_exp2(float x) {
    return __builtin_amdgcn_exp2f(x);
}

// Kernel 1: Wq/Wk -> bf16 fragment-major.
__global__ void wt_kernel(const float* __restrict__ Wq, const float* __restrict__ Wk,
                          bf16_t* __restrict__ wtf) {
    int idx = blockIdx.x * 256 + threadIdx.x;   // [0, 16384)
    int w    = idx >> 13;
    int rem  = idx & 8191;
    int nt   = rem >> 9;
    int rem2 = rem & 511;
    int ks   = rem2 >> 6;
    int lane = rem2 & 63;
    int lm = lane & 15, lg = lane >> 4;
    const float* Wsrc = (w == 0) ? Wq : Wk;
    int col = nt * 16 + lm, krow = ks * 32 + lg * 8;
    bf16x8 o;
#pragma unroll
    for (int j = 0; j < 8; j++) o[j] = (bf16_t)Wsrc[(krow + j) * 256 + col];
    *(bf16x8*)(wtf + (size_t)idx * 8) = o;
}

// Kernel 1b: x (fp32 row-major) -> xf (bf16 fragment-major). grid 512 x 256.
// One wave per 16-row qb tile: coalesced row reads -> wave-private LDS
// transpose -> contiguous 1KB frag stores. Pure-bandwidth (~84 MB).
__global__ __launch_bounds__(256) void xconv_kernel(
    const float* __restrict__ x, bf16_t* __restrict__ xf) {
    __shared__ bf16_t xt[4][4096];           // 8 KB per wave
    int tid = threadIdx.x, wave = tid >> 6, lane = tid & 63;
    int qb = blockIdx.x * 4 + wave;          // [0, 2048)
    const float* xr = x + (size_t)qb * 16 * 256;
    bf16_t* buf = xt[wave];
    int ks = lane >> 3, lg = (lane & 7) >> 1, j = (lane & 1) * 4;
#pragma unroll
    for (int rr = 0; rr < 16; rr++) {
        float4 f = *(const float4*)(xr + rr * 256 + lane * 4);
        bf16x4 o;
        o[0] = (bf16_t)f.x; o[1] = (bf16_t)f.y; o[2] = (bf16_t)f.z; o[3] = (bf16_t)f.w;
        *(bf16x4*)&buf[(ks * 64 + lg * 16 + rr) * 8 + j] = o;
    }
    // wave-private LDS: DS pipe in-order per wave, no barrier needed
    bf16_t* dst = xf + (size_t)qb * 4096;
#pragma unroll
    for (int k2 = 0; k2 < 8; k2++) {
        bf16x8 v = *(const bf16x8*)&buf[k2 * 512 + lane * 8];
        *(bf16x8*)(dst + k2 * 512 + lane * 8) = v;
    }
}

// Kernel 2: Q/K projection, GEMM-tiled. grid (512 = 256 rowb x 2 colh, 2 w),
// 256 thr (4 waves as 2 rowg x 2 colg). Block tile 128 rows x 128 cols.
// B-frags (64 KB) staged to LDS once; A-frags are CONTIGUOUS lane*16B bursts
// from xf (this is the R9 fix: scattered x gathers killed the MFMA pipe).
__global__ __launch_bounds__(256, 2) void proj_kernel(
    const bf16_t* __restrict__ xf, const bf16_t* __restrict__ wtf,
    const float* __restrict__ bq, const float* __restrict__ bk,
    bf16_t* __restrict__ qo, bf16_t* __restrict__ ko) {
    __shared__ bf16_t bst[32768];          // 8 nt x 8 ks x 512  (64 KB)
    __shared__ bf16_t sb_all[4][1152];     // epilogue transpose: 16 x 72 per wave
    int w    = blockIdx.y;
    int tid  = threadIdx.x;
    int wave = tid >> 6, lane = tid & 63, lm = lane & 15, lg = lane >> 4;
    int rowb = blockIdx.x >> 1;
    int colh = blockIdx.x & 1;
    int rowg = wave >> 1, colg = wave & 1;
    const float* bias = (w == 0) ? bq : bk;

    // ---- stage this col-half's B-frags (64 KB), 4 rounds of 4 ----
    {
        const bf16_t* src = wtf + w * 65536 + (size_t)colh * 32768;
#pragma unroll
        for (int rnd = 0; rnd < 4; rnd++) {
            bf16x8 tmp[4];
#pragma unroll
            for (int u = 0; u < 4; u++)
                tmp[u] = *(const bf16x8*)(src + (size_t)((rnd * 4 + u) * 256 + tid) * 8);
#pragma unroll
            for (int u = 0; u < 4; u++)
                *(bf16x8*)&bst[(size_t)((rnd * 4 + u) * 256 + tid) * 8] = tmp[u];
        }
    }

    // ---- A-frags: 4 sets x 16 rows, contiguous from xf ----
    int qb0 = rowb * 8 + rowg * 4;        // global qb for set 0
    bf16x8 af[4][8];
#pragma unroll
    for (int s = 0; s < 4; s++) {
        const bf16_t* ab = xf + (size_t)(qb0 + s) * 4096;
#pragma unroll
        for (int ks = 0; ks < 8; ks++)
            af[s][ks] = *(const bf16x8*)(ab + ks * 512 + lane * 8);
    }
    __syncthreads();

    // ---- MFMA: 4 sets x 4 nt x 8 ks = 128 MFMAs, B from LDS (reuse 4) ----
    f32x4 acc[4][4];
#pragma unroll
    for (int s = 0; s < 4; s++)
#pragma unroll
        for (int nt = 0; nt < 4; nt++) acc[s][nt] = f32x4{0.f, 0.f, 0.f, 0.f};
#pragma unroll
    for (int ks = 0; ks < 8; ks++) {
#pragma unroll
        for (int nt = 0; nt < 4; nt++) {
            bf16x8 bfr = *(const bf16x8*)&bst[(size_t)(((colg * 4 + nt) * 8 + ks) * 512) + lane * 8];
#pragma unroll
            for (int s = 0; s < 4; s++)
                acc[s][nt] = __builtin_amdgcn_mfma_f32_16x16x32_bf16(af[s][ks], bfr, acc[s][nt], 0, 0, 0);
        }
    }

    // ---- epilogue: wave-private LDS transpose -> frag-major 16B stores ----
    bf16_t* sb = sb_all[wave];
    bf16_t* dst = (w == 0) ? qo : ko;
    int c0 = colh * 128 + colg * 64;
#pragma unroll
    for (int s = 0; s < 4; s++) {
#pragma unroll
        for (int nt = 0; nt < 4; nt++) {
            int colloc = nt * 16 + lm;
            float bval = bias[c0 + colloc];
#pragma unroll
            for (int r = 0; r < 4; r++)
                sb[(lg * 4 + r) * 72 + colloc] = (bf16_t)(acc[s][nt][r] + bval);
        }
#pragma unroll
        for (int kk = 0; kk < 2; kk++) {
            bf16x8 v8 = *(const bf16x8*)&sb[lm * 72 + kk * 32 + lg * 8];
            *(bf16x8*)(dst + ((size_t)((qb0 + s) * 8 + (c0 >> 5) + kk)) * 512 + lane * 8) = v8;
        }
    }
}

// Kernels 3/4: QK^T passes. grid 256 = (16 b x 4 qt(512 rows) x 4 kh(512 keys)),
// 512 thr (8 waves). Wave owns 64 q-rows (4 A-sets in regs -> B-frag reuse 4);
// 64-key K tiles staged to LDS (2x32KB dbuf), shared by 8 waves.
// PASS=1: row-sums l -> lpart.  PASS=2: w_k = sum_q p/l -> wpart.
template <int PASS>
__global__ __launch_bounds__(512, 2) void attn_pass(
    const bf16_t* __restrict__ q, const bf16_t* __restrict__ kmat,
    float* __restrict__ lpart, float* __restrict__ wpart) {
    __shared__ bf16_t kst[2][16384];          // 2 x 32 KB
    __shared__ bf16_t wacc[8][512];           // PASS 2 only

    int tid  = threadIdx.x;
    int wave = tid >> 6, lane = tid & 63, lm = lane & 15, lg = lane >> 4;
    int i    = blockIdx.x;                    // 256 blocks
    int idx2 = i >> 3;                        // 0..31
    int qt   = idx2 & 3;
    int kh   = (idx2 >> 2) & 3;
    int b    = (i & 7) * 2 + (idx2 >> 4);     // XCD-aware: 2 batches per XCD

    bf16x8 af[4][8];
#pragma unroll
    for (int s = 0; s < 4; s++) {
        const bf16_t* qb = q + ((size_t)((b * 128 + qt * 32 + wave * 4 + s) * 8)) * 512;
#pragma unroll
        for (int ks = 0; ks < 8; ks++)
            af[s][ks] = *(const bf16x8*)(qb + ks * 512 + lane * 8);
    }

    float rinv[4][4];
    if (PASS == 2) {
#pragma unroll
        for (int s = 0; s < 4; s++)
#pragma unroll
            for (int r = 0; r < 4; r++) {
                int row = qt * 512 + wave * 64 + s * 16 + lg * 4 + r;
                float l = 0.f;
#pragma unroll
                for (int k2 = 0; k2 < 4; k2++)
                    l += lpart[(size_t)(k2 * 16 + b) * 2048 + row];
                rinv[s][r] = 1.0f / l;
            }
    }

    float lsum[4][4];
#pragma unroll
    for (int s = 0; s < 4; s++)
#pragma unroll
        for (int r = 0; r < 4; r++) lsum[s][r] = 0.f;

    constexpr float SCL = 0.0625f * 1.44269504f;
    const bf16_t* kb_base = kmat + (size_t)(b * 128 + kh * 32) * 4096;

    bf16x8 stg[4];
#pragma unroll
    for (int u = 0; u < 4; u++)
        stg[u] = *(const bf16x8*)(kb_base + (size_t)(u * 512 + tid) * 8);

    for (int t = 0; t < 8; t++) {
        int p = t & 1;
#pragma unroll
        for (int u = 0; u < 4; u++)
            *(bf16x8*)&kst[p][(u * 512 + tid) * 8] = stg[u];
        if (t < 7) {
#pragma unroll
            for (int u = 0; u < 4; u++)
                stg[u] = *(const bf16x8*)(kb_base + (size_t)(t + 1) * 16384 + (u * 512 + tid) * 8);
        }
        __syncthreads();

#pragma unroll
        for (int h = 0; h < 2; h++) {
            f32x4 sacc[4][2];
#pragma unroll
            for (int s = 0; s < 4; s++) {
                sacc[s][0] = f32x4{0.f, 0.f, 0.f, 0.f};
                sacc[s][1] = f32x4{0.f, 0.f, 0.f, 0.f};
            }
#pragma unroll
            for (int ks = 0; ks < 8; ks++) {
                bf16x8 b0 = *(const bf16x8*)&kst[p][((h * 2 + 0) * 8 + ks) * 512 + lane * 8];
                bf16x8 b1 = *(const bf16x8*)&kst[p][((h * 2 + 1) * 8 + ks) * 512 + lane * 8];
#pragma unroll
                for (int s = 0; s < 4; s++) {
                    sacc[s][0] = __builtin_amdgcn_mfma_f32_16x16x32_bf16(af[s][ks], b0, sacc[s][0], 0, 0, 0);
                    sacc[s][1] = __builtin_amdgcn_mfma_f32_16x16x32_bf16(af[s][ks], b1, sacc[s][1], 0, 0, 0);
                }
            }
            if (PASS == 1) {
#pragma unroll
                for (int s = 0; s < 4; s++)
#pragma unroll
                    for (int j = 0; j < 2; j++)
#pragma unroll
                        for (int r = 0; r < 4; r++)
                            lsum[s][r] += fast_exp2(sacc[s][j][r] * SCL);
            } else {
#pragma unroll
                for (int j = 0; j < 2; j++) {
                    float wv = 0.f;
#pragma unroll
                    for (int s = 0; s < 4; s++)
#pragma unroll
                        for (int r = 0; r < 4; r++)
                            wv += fast_exp2(sacc[s][j][r] * SCL) * rinv[s][r];
                    wv += __shfl_xor(wv, 16);
                    wv += __shfl_xor(wv, 32);
                    if (lg == 0) wacc[wave][t * 64 + (h * 2 + j) * 16 + lm] = (bf16_t)wv;
                }
            }
        }
    }

    if (PASS == 1) {
#pragma unroll
        for (int s = 0; s < 4; s++)
#pragma unroll
            for (int r = 0; r < 4; r++) {
                float v2 = lsum[s][r];
                v2 += __shfl_xor(v2, 1);
                v2 += __shfl_xor(v2, 2);
                v2 += __shfl_xor(v2, 4);
                v2 += __shfl_xor(v2, 8);
                if (lm == 0) {
                    int row = qt * 512 + wave * 64 + s * 16 + lg * 4 + r;
                    lpart[(size_t)(kh * 16 + b) * 2048 + row] = v2;
                }
            }
    } else {
        __syncthreads();
        float sum = 0.f;
#pragma unroll
        for (int w2 = 0; w2 < 8; w2++) sum += (float)wacc[w2][tid];
        wpart[(size_t)(qt * 16 + b) * 2048 + kh * 512 + tid] = sum;
    }
}

// Kernel 5: gpart[kseg,b,d] = sum over 128 keys of w_k x[b,k,d] (fp32 x).
__global__ __launch_bounds__(256) void xsum_kernel(
    const float* __restrict__ wpart, const float* __restrict__ x,
    float* __restrict__ gpart) {
    __shared__ float ldsw[128];
    int b = blockIdx.x >> 4, kseg = blockIdx.x & 15, tid = threadIdx.x;
    if (tid < 128) {
        int key = kseg * 128 + tid;
        float s = 0.f;
#pragma unroll
        for (int qt = 0; qt < 4; qt++) s += wpart[(size_t)(qt * 16 + b) * 2048 + key];
        ldsw[tid] = s;
    }
    __syncthreads();
    const float* xb = x + ((size_t)b * 2048 + kseg * 128) * 256;
    float acc = 0.f;
#pragma unroll 8
    for (int t = 0; t < 128; t++) acc += ldsw[t] * xb[(size_t)t * 256 + tid];
    gpart[(size_t)(kseg * 16 + b) * 256 + tid] = acc;
}

// Kernel 6: out[b,d] = (sum_kseg gpart)[b,:] @ Wv[:,d] + 2048*bv[d].
__global__ __launch_bounds__(256) void final_kernel(
    const float* __restrict__ gpart, const float* __restrict__ Wv,
    const float* __restrict__ bv, float* __restrict__ out) {
    __shared__ float yl[256];
    int b = blockIdx.x, tid = threadIdx.x;
    float s = 0.f;
#pragma unroll
    for (int ks = 0; ks < 16; ks++) s += gpart[(size_t)(ks * 16 + b) * 256 + tid];
    yl[tid] = s;
    __syncthreads();
    float acc = 0.f;
#pragma unroll 4
    for (int c = 0; c < 256; c++) acc += yl[c] * Wv[c * 256 + tid];
    out[b * 256 + tid] = acc + 2048.0f * bv[tid];
}

extern "C" void kernel_launch(void* const* d_in, const int* in_sizes, int n_in,
                              void* d_out, int out_size, void* d_ws, size_t ws_size,
                              hipStream_t stream) {
    const float* x  = (const float*)d_in[0];
    const float* Wq = (const float*)d_in[1];
    const float* bq = (const float*)d_in[2];
    const float* Wk = (const float*)d_in[3];
    const float* bk = (const float*)d_in[4];
    const float* Wv = (const float*)d_in[5];
    const float* bv = (const float*)d_in[6];
    float* out = (float*)d_out;

    char* ws = (char*)d_ws;
    bf16_t* wtf   = (bf16_t*)(ws);
    bf16_t* xf    = (bf16_t*)(ws + 262144);
    bf16_t* q     = (bf16_t*)(ws + 17039360);
    bf16_t* kmat  = (bf16_t*)(ws + 33816576);
    float*  lpart = (float*) (ws + 50593792);
    float*  wpart = (float*) (ws + 51118080);
    float*  gpart = (float*) (ws + 51642368);

    wt_kernel<<<dim3(64), dim3(256), 0, stream>>>(Wq, Wk, wtf);
    xconv_kernel<<<dim3(512), dim3(256), 0, stream>>>(x, xf);
    proj_kernel<<<dim3(512, 2), dim3(256), 0, stream>>>(xf, wtf, bq, bk, q, kmat);
    attn_pass<1><<<dim3(256), dim3(512), 0, stream>>>(q, kmat, lpart, wpart);
    attn_pass<2><<<dim3(256), dim3(512), 0, stream>>>(q, kmat, lpart, wpart);
    xsum_kernel<<<dim3(256), dim3(256), 0, stream>>>(wpart, x, gpart);
    final_kernel<<<dim3(16), dim3(256), 0, stream>>>(gpart, Wv, bv, out);
}